// Round 8
// baseline (304.252 us; speedup 1.0000x reference)
//
#include <hip/hip_runtime.h>
#include <hip/hip_bf16.h>

#define BATCH 2
#define SEQ   2048
#define DIM   2048
#define NHEAD 16
#define HDIM  128

// LDS strides (elements). Multiples of 8 (16B alignment for b128); bank
// audits at each access site (all patterns <=4-way, most 2-way/free).
#define KSTRIDE 136
#define VSTRIDE 72
#define PSTRIDE 72

typedef __bf16 bf16;
typedef __attribute__((ext_vector_type(2))) __bf16 bf16x2;
typedef __attribute__((ext_vector_type(4))) __bf16 bf16x4;
typedef __attribute__((ext_vector_type(8))) __bf16 bf16x8;
typedef __attribute__((ext_vector_type(4))) float f32x4;

__device__ __forceinline__ void load_lds16(const bf16* g, bf16* l) {
    __builtin_amdgcn_global_load_lds((const __attribute__((address_space(1))) void*)g,
                                     (__attribute__((address_space(3))) void*)l, 16, 0, 0);
}

// v_exp_f32: D = 2^S0 (hardware transcendental)
__device__ __forceinline__ float exp2_hw(float x) { return __builtin_amdgcn_exp2f(x); }

// ---------------------------------------------------------------------------
// cvt: fp32 -> bf16 elementwise (x staging)
// ---------------------------------------------------------------------------
__global__ __launch_bounds__(256)
void cvt_bf16(const float* __restrict__ x, bf16* __restrict__ xb, int n4)
{
    const int i = blockIdx.x * 256 + threadIdx.x;
    if (i < n4) {
        const float4 f = ((const float4*)x)[i];
        ((bf16x4*)xb)[i] = (bf16x4){(bf16)f.x, (bf16)f.y, (bf16)f.z, (bf16)f.w};
    }
}

// ---------------------------------------------------------------------------
// transpose+convert: W[K][N] fp32 -> Wt[N][K] bf16. 64x64 LDS tile, padded.
// ---------------------------------------------------------------------------
__global__ __launch_bounds__(256)
void transpose_w(const float* __restrict__ W, bf16* __restrict__ Wt)
{
    __shared__ bf16 T[64][72];
    const int kb = blockIdx.y * 64, nb = blockIdx.x * 64;
    const int r  = threadIdx.x >> 2;          // 0..63
    const int c0 = (threadIdx.x & 3) * 16;    // 0,16,32,48
    #pragma unroll
    for (int i = 0; i < 16; i += 4) {
        const float4 f = *(const float4*)(W + (size_t)(kb + r) * DIM + nb + c0 + i);
        T[r][c0 + i + 0] = (bf16)f.x;
        T[r][c0 + i + 1] = (bf16)f.y;
        T[r][c0 + i + 2] = (bf16)f.z;
        T[r][c0 + i + 3] = (bf16)f.w;
    }
    __syncthreads();
    bf16x8 o0, o1;
    #pragma unroll
    for (int i = 0; i < 8; ++i) { o0[i] = T[c0 + i][r]; o1[i] = T[c0 + 8 + i][r]; }
    *(bf16x8*)(Wt + (size_t)(nb + r) * DIM + kb + c0)     = o0;
    *(bf16x8*)(Wt + (size_t)(nb + r) * DIM + kb + c0 + 8) = o1;
}

// ---------------------------------------------------------------------------
// GEMM: C[M,N] = A[M,K] @ Bt[N,K]^T, bf16 in. BK=64 (two [128][32] half
// buffers keep the m97 bank layout). 128x128 tile, 4 waves 2x2, 4x4 accs,
// global_load_lds width=16.
// ---------------------------------------------------------------------------
template<bool OUT_F32_BIAS>
__global__ __launch_bounds__(256)
void gemm_bt(const bf16* __restrict__ A, const bf16* __restrict__ Bt,
             const float* __restrict__ bias, void* __restrict__ Cptr,
             int M, int N, int K)
{
    __shared__ bf16 As[2][128 * 32];   // [k-half][row][32]
    __shared__ bf16 Bs[2][128 * 32];

    const int tid  = threadIdx.x;
    const int wave = tid >> 6;
    const int lane = tid & 63;
    const int quad = lane >> 4;
    const int l16  = lane & 15;
    const int wr   = (wave >> 1) * 64;
    const int wc   = (wave & 1) * 64;
    const int rowBase = blockIdx.y * 128;
    const int colBase = blockIdx.x * 128;

    const int srow = lane >> 2;
    const int scol = (lane & 3) * 8;
    const bf16* aBase = A  + (size_t)(rowBase + wave * 16 + srow) * K + scol;
    const bf16* bBase = Bt + (size_t)(colBase + wave * 16 + srow) * K + scol;

    f32x4 acc[4][4] = {};

    for (int k0 = 0; k0 < K; k0 += 64) {
        #pragma unroll
        for (int rh = 0; rh < 2; ++rh) {
            #pragma unroll
            for (int kh = 0; kh < 2; ++kh) {
                load_lds16(aBase + (size_t)rh * 64 * K + k0 + kh * 32,
                           (bf16*)As[kh] + (rh * 64 + wave * 16) * 32);
                load_lds16(bBase + (size_t)rh * 64 * K + k0 + kh * 32,
                           (bf16*)Bs[kh] + (rh * 64 + wave * 16) * 32);
            }
        }
        __syncthreads();

        #pragma unroll
        for (int ks = 0; ks < 2; ++ks) {
            bf16x8 a[4], b[4];
            #pragma unroll
            for (int i = 0; i < 4; ++i)
                a[i] = *(const bf16x8*)&As[ks][(wr + i * 16 + l16) * 32 + quad * 8];
            #pragma unroll
            for (int j = 0; j < 4; ++j)
                b[j] = *(const bf16x8*)&Bs[ks][(wc + j * 16 + l16) * 32 + quad * 8];
            #pragma unroll
            for (int i = 0; i < 4; ++i)
                #pragma unroll
                for (int j = 0; j < 4; ++j)
                    acc[i][j] = __builtin_amdgcn_mfma_f32_16x16x32_bf16(a[i], b[j], acc[i][j], 0, 0, 0);
        }
        __syncthreads();
    }

    #pragma unroll
    for (int i = 0; i < 4; ++i) {
        #pragma unroll
        for (int j = 0; j < 4; ++j) {
            #pragma unroll
            for (int r = 0; r < 4; ++r) {
                const int row = rowBase + wr + i * 16 + quad * 4 + r;
                const int col = colBase + wc + j * 16 + l16;
                const float v = acc[i][j][r];
                if (OUT_F32_BIAS) ((float*)Cptr)[(size_t)row * N + col] = v + bias[col];
                else              ((bf16*)Cptr)[(size_t)row * N + col] = (bf16)v;
            }
        }
    }
}

// ---------------------------------------------------------------------------
// Attention, round 8: S^T-form, q-tile 256, 4 waves x 64 q-rows, 1 block/CU.
// Halves the per-CU LDS traffic vs round 7 (staging once per CU-iter, K/V
// fragment duplication amortized over 2x the q-rows). Register prefetch of
// the next K/V tile kept from round 7. __launch_bounds__(256,1) -> 512
// regs/wave so aq[4][4]+yacc[4][8] (~280 live) does NOT spill (round-5 bug).
// ---------------------------------------------------------------------------
__global__ __launch_bounds__(256, 1)
void attn_kernel(const bf16* __restrict__ q, bf16* __restrict__ y)
{
    __shared__ bf16 Ks[64 * KSTRIDE];     // 17408 B  [kv][hd]
    __shared__ bf16 Vt[HDIM * VSTRIDE];   // 18432 B  [hd][kv]
    __shared__ bf16 Ps[256 * PSTRIDE];    // 36864 B  [q][kv]

    const int tid  = threadIdx.x;
    const int wave = tid >> 6;     // 0..3
    const int lane = tid & 63;
    const int quad = lane >> 4;
    const int l16  = lane & 15;

    const int qt = blockIdx.x;
    const int h  = blockIdx.y;
    const int bb = blockIdx.z;

    const bf16* qb = q + (size_t)bb * SEQ * DIM + (size_t)h * HDIM;

    // Q fragments -> registers (wave owns q rows [wave*64, wave*64+64)).
    const float qs = 0.12752820031096662f;   // (1/sqrt(128)) * log2(e)
    bf16x8 aq[4][4];
    #pragma unroll
    for (int nt = 0; nt < 4; ++nt) {
        #pragma unroll
        for (int ks = 0; ks < 4; ++ks) {
            const bf16* src = qb + (size_t)(qt * 256 + wave * 64 + nt * 16 + l16) * DIM + ks * 32 + quad * 8;
            bf16x8 v = *(const bf16x8*)src;
            bf16x8 o;
            #pragma unroll
            for (int e = 0; e < 8; ++e) o[e] = (bf16)((float)v[e] * qs);
            aq[nt][ks] = o;
        }
    }

    float lpart[4] = {0.f, 0.f, 0.f, 0.f};
    f32x4 yacc[4][8] = {};

    // staging index maps (conflict-free; round-6 audit)
    const int kr   = tid >> 2;         // kv row 0..63 (Ks path)
    const int koff = (tid & 3) * 32;
    const int sp   = tid & 31;         // kv pair (Vt path)
    const int ss   = tid >> 5;         // hd slice of 16

    const bf16* srcK = qb + (size_t)kr * DIM + koff;
    const bf16* srcV = qb + (size_t)(2 * sp) * DIM + ss * 16;

    // prologue: prefetch tile 0 into registers
    bf16x8 kreg[4], va[2], vb[2];
    #pragma unroll
    for (int c = 0; c < 4; ++c) kreg[c] = *(const bf16x8*)(srcK + c * 8);
    va[0] = *(const bf16x8*)(srcV + 0);
    va[1] = *(const bf16x8*)(srcV + 8);
    vb[0] = *(const bf16x8*)(srcV + DIM + 0);
    vb[1] = *(const bf16x8*)(srcV + DIM + 8);

    for (int kt = 0; kt < SEQ / 64; ++kt) {
        __syncthreads();   // prev iteration done reading Ks/Vt

        // commit prefetched tile to LDS
        #pragma unroll
        for (int c = 0; c < 4; ++c)
            *(bf16x8*)&Ks[kr * KSTRIDE + koff + c * 8] = kreg[c];
        #pragma unroll
        for (int c = 0; c < 2; ++c)
            #pragma unroll
            for (int e = 0; e < 8; ++e)
                *(bf16x2*)&Vt[(ss * 16 + c * 8 + e) * VSTRIDE + 2 * sp] = (bf16x2){va[c][e], vb[c][e]};

        // prefetch NEXT tile (overlaps the compute phase below)
        if (kt + 1 < SEQ / 64) {
            const bf16* nK = srcK + (size_t)(kt + 1) * 64 * DIM;
            const bf16* nV = srcV + (size_t)(kt + 1) * 64 * DIM;
            #pragma unroll
            for (int c = 0; c < 4; ++c) kreg[c] = *(const bf16x8*)(nK + c * 8);
            va[0] = *(const bf16x8*)(nV + 0);
            va[1] = *(const bf16x8*)(nV + 8);
            vb[0] = *(const bf16x8*)(nV + DIM + 0);
            vb[1] = *(const bf16x8*)(nV + DIM + 8);
        }
        __syncthreads();

        // S^T phase per 16-kv strip (mt): MFMA(A=Ks-frag, B=aq).
        // C-layout of S^T: kv = mt*16 + quad*4 + r, q = wave*64 + nt*16 + l16.
        #pragma unroll
        for (int mt = 0; mt < 4; ++mt) {
            bf16x8 ak[4];
            #pragma unroll
            for (int ks = 0; ks < 4; ++ks)
                ak[ks] = *(const bf16x8*)&Ks[(mt * 16 + l16) * KSTRIDE + ks * 32 + quad * 8];
            f32x4 s[4] = {};
            #pragma unroll
            for (int ks = 0; ks < 4; ++ks)
                #pragma unroll
                for (int nt = 0; nt < 4; ++nt)
                    s[nt] = __builtin_amdgcn_mfma_f32_16x16x32_bf16(ak[ks], aq[nt][ks], s[nt], 0, 0, 0);
            #pragma unroll
            for (int nt = 0; nt < 4; ++nt) {
                float p0 = exp2_hw(s[nt][0]);
                float p1 = exp2_hw(s[nt][1]);
                float p2 = exp2_hw(s[nt][2]);
                float p3 = exp2_hw(s[nt][3]);
                lpart[nt] += (p0 + p1) + (p2 + p3);
                *(bf16x4*)&Ps[(wave * 64 + nt * 16 + l16) * PSTRIDE + mt * 16 + quad * 4] =
                    (bf16x4){(bf16)p0, (bf16)p1, (bf16)p2, (bf16)p3};
            }
        }

        // PV: Y += P @ V. A = own-wave P rows (in-wave LDS dep only), B = V^T.
        #pragma unroll
        for (int ks2 = 0; ks2 < 2; ++ks2) {
            bf16x8 ap[4];
            #pragma unroll
            for (int i = 0; i < 4; ++i)
                ap[i] = *(const bf16x8*)&Ps[(wave * 64 + i * 16 + l16) * PSTRIDE + ks2 * 32 + quad * 8];
            #pragma unroll
            for (int n = 0; n < 8; ++n) {
                bf16x8 bv = *(const bf16x8*)&Vt[(n * 16 + l16) * VSTRIDE + ks2 * 32 + quad * 8];
                #pragma unroll
                for (int i = 0; i < 4; ++i)
                    yacc[i][n] = __builtin_amdgcn_mfma_f32_16x16x32_bf16(ap[i], bv, yacc[i][n], 0, 0, 0);
            }
        }
    }

    // denominators: lane holds partial over its 16 kv per q = nt*16 + l16;
    // reduce across the 4 quad-lanes sharing each q.
    float lfull[4];
    #pragma unroll
    for (int nt = 0; nt < 4; ++nt) {
        float l = lpart[nt];
        l += __shfl_xor(l, 16);
        l += __shfl_xor(l, 32);
        lfull[nt] = l;
    }

    // epilogue: yacc C-layout row = wave*64 + i*16 + quad*4 + r (q),
    // col = n*16 + l16 (hd).
    bf16* yb = y + (size_t)bb * SEQ * DIM + (size_t)(qt * 256) * DIM + (size_t)h * HDIM;
    #pragma unroll
    for (int i = 0; i < 4; ++i) {
        #pragma unroll
        for (int r = 0; r < 4; ++r) {
            const float lv  = __shfl(lfull[i], (lane & 48) | (quad * 4 + r));
            const float inv = 1.f / lv;
            const int row = wave * 64 + i * 16 + quad * 4 + r;
            #pragma unroll
            for (int n = 0; n < 8; ++n)
                yb[(size_t)row * DIM + n * 16 + l16] = (bf16)(yacc[i][n][r] * inv);
        }
    }
}

// ---------------------------------------------------------------------------
extern "C" void kernel_launch(void* const* d_in, const int* in_sizes, int n_in,
                              void* d_out, int out_size, void* d_ws, size_t ws_size,
                              hipStream_t stream)
{
    const float* x  = (const float*)d_in[0];
    const float* Wq = (const float*)d_in[1];
    const float* Wo = (const float*)d_in[2];
    const float* bo = (const float*)d_in[3];
    float* out = (float*)d_out;

    const size_t NELEM = (size_t)BATCH * SEQ * DIM;
    bf16* qws = (bf16*)d_ws;
    bf16* xb  = qws + NELEM;        // reused as yws after gemm1
    bf16* yws = xb;
    bf16* Wt  = xb + NELEM;

    const int M = BATCH * SEQ;
    dim3 gg(DIM / 128, M / 128);
    dim3 gt(DIM / 64, DIM / 64);

    cvt_bf16<<<(int)(NELEM / 4 + 255) / 256, 256, 0, stream>>>(x, xb, (int)(NELEM / 4));
    transpose_w<<<gt, 256, 0, stream>>>(Wq, Wt);
    gemm_bt<false><<<gg, 256, 0, stream>>>(xb, Wt, nullptr, qws, M, DIM, DIM);
    transpose_w<<<gt, 256, 0, stream>>>(Wo, Wt);
    attn_kernel<<<dim3(SEQ / 256, NHEAD, BATCH), 256, 0, stream>>>(qws, yws);
    gemm_bt<true><<<gg, 256, 0, stream>>>(yws, Wt, bo, out, M, DIM, DIM);
}

// Round 9
// 285.108 us; speedup vs baseline: 1.0671x; 1.0671x over previous
//
#include <hip/hip_runtime.h>
#include <hip/hip_bf16.h>

#define BATCH 2
#define SEQ   2048
#define DIM   2048
#define NHEAD 16
#define HDIM  128

// LDS strides (elements). Multiples of 8 (16B alignment for b128); bank
// audits in comments at each access site.
#define KSTRIDE 136
#define VSTRIDE 72
#define PSTRIDE 72

typedef __bf16 bf16;
typedef __attribute__((ext_vector_type(2))) __bf16 bf16x2;
typedef __attribute__((ext_vector_type(4))) __bf16 bf16x4;
typedef __attribute__((ext_vector_type(8))) __bf16 bf16x8;
typedef __attribute__((ext_vector_type(4))) float f32x4;

__device__ __forceinline__ void load_lds16(const bf16* g, bf16* l) {
    __builtin_amdgcn_global_load_lds((const __attribute__((address_space(1))) void*)g,
                                     (__attribute__((address_space(3))) void*)l, 16, 0, 0);
}

// v_exp_f32: D = 2^S0 (hardware transcendental)
__device__ __forceinline__ float exp2_hw(float x) { return __builtin_amdgcn_exp2f(x); }

// ---------------------------------------------------------------------------
// cvt: fp32 -> bf16 elementwise (x staging)
// ---------------------------------------------------------------------------
__global__ __launch_bounds__(256)
void cvt_bf16(const float* __restrict__ x, bf16* __restrict__ xb, int n4)
{
    const int i = blockIdx.x * 256 + threadIdx.x;
    if (i < n4) {
        const float4 f = ((const float4*)x)[i];
        ((bf16x4*)xb)[i] = (bf16x4){(bf16)f.x, (bf16)f.y, (bf16)f.z, (bf16)f.w};
    }
}

// ---------------------------------------------------------------------------
// transpose+convert v2: W[K][N] fp32 -> Wt[N][K] bf16. 64x64 tile.
// Transpose happens on the WRITE side with paired-k b32 writes:
//   lane (a = tid&31 -> k-pair {2a,2a+1}, g = tid>>5 -> n-slice g*8..g*8+8)
//   bank = (36*(8g+i) + a) mod 32; 36*8 = 288 = 0 mod 32 -> a spans all 32
//   banks, 2-way across g cohorts = free.
// Read side: row reads T[n][k0..k0+16] as 2x b128 (baseline bank spread),
// stores coalesced bf16x8. Replaces the old 8-way-conflicted column reads.
// ---------------------------------------------------------------------------
__global__ __launch_bounds__(256)
void transpose_w(const float* __restrict__ W, bf16* __restrict__ Wt)
{
    __shared__ bf16 T[64 * 72];   // [n][k], stride 72
    const int kb = blockIdx.y * 64, nb = blockIdx.x * 64;

    const int a = threadIdx.x & 31;     // k-pair index
    const int g = threadIdx.x >> 5;     // n-slice 0..7

    {
        const float* s0 = W + (size_t)(kb + 2 * a) * DIM + nb + g * 8;
        const float4 r0a = *(const float4*)(s0);
        const float4 r0b = *(const float4*)(s0 + 4);
        const float4 r1a = *(const float4*)(s0 + DIM);
        const float4 r1b = *(const float4*)(s0 + DIM + 4);
        float v0[8] = {r0a.x, r0a.y, r0a.z, r0a.w, r0b.x, r0b.y, r0b.z, r0b.w};
        float v1[8] = {r1a.x, r1a.y, r1a.z, r1a.w, r1b.x, r1b.y, r1b.z, r1b.w};
        #pragma unroll
        for (int i = 0; i < 8; ++i)
            *(bf16x2*)&T[(g * 8 + i) * 72 + 2 * a] = (bf16x2){(bf16)v0[i], (bf16)v1[i]};
    }
    __syncthreads();

    const int r  = threadIdx.x >> 2;          // output n row 0..63
    const int k0 = (threadIdx.x & 3) * 16;    // k chunk
    bf16x8 o0 = *(const bf16x8*)&T[r * 72 + k0];
    bf16x8 o1 = *(const bf16x8*)&T[r * 72 + k0 + 8];
    *(bf16x8*)(Wt + (size_t)(nb + r) * DIM + kb + k0)     = o0;
    *(bf16x8*)(Wt + (size_t)(nb + r) * DIM + kb + k0 + 8) = o1;
}

// ---------------------------------------------------------------------------
// GEMM: C[M,N] = A[M,K] @ Bt[N,K]^T, bf16 in. BK=64 (two [128][32] half
// buffers keep the m97 bank layout). 128x128 tile, 4 waves 2x2, 4x4 accs,
// global_load_lds width=16.
// ---------------------------------------------------------------------------
template<bool OUT_F32_BIAS>
__global__ __launch_bounds__(256)
void gemm_bt(const bf16* __restrict__ A, const bf16* __restrict__ Bt,
             const float* __restrict__ bias, void* __restrict__ Cptr,
             int M, int N, int K)
{
    __shared__ bf16 As[2][128 * 32];   // [k-half][row][32]
    __shared__ bf16 Bs[2][128 * 32];

    const int tid  = threadIdx.x;
    const int wave = tid >> 6;
    const int lane = tid & 63;
    const int quad = lane >> 4;
    const int l16  = lane & 15;
    const int wr   = (wave >> 1) * 64;
    const int wc   = (wave & 1) * 64;
    const int rowBase = blockIdx.y * 128;
    const int colBase = blockIdx.x * 128;

    const int srow = lane >> 2;
    const int scol = (lane & 3) * 8;
    const bf16* aBase = A  + (size_t)(rowBase + wave * 16 + srow) * K + scol;
    const bf16* bBase = Bt + (size_t)(colBase + wave * 16 + srow) * K + scol;

    f32x4 acc[4][4] = {};

    for (int k0 = 0; k0 < K; k0 += 64) {
        #pragma unroll
        for (int rh = 0; rh < 2; ++rh) {
            #pragma unroll
            for (int kh = 0; kh < 2; ++kh) {
                load_lds16(aBase + (size_t)rh * 64 * K + k0 + kh * 32,
                           (bf16*)As[kh] + (rh * 64 + wave * 16) * 32);
                load_lds16(bBase + (size_t)rh * 64 * K + k0 + kh * 32,
                           (bf16*)Bs[kh] + (rh * 64 + wave * 16) * 32);
            }
        }
        __syncthreads();

        #pragma unroll
        for (int ks = 0; ks < 2; ++ks) {
            bf16x8 a[4], b[4];
            #pragma unroll
            for (int i = 0; i < 4; ++i)
                a[i] = *(const bf16x8*)&As[ks][(wr + i * 16 + l16) * 32 + quad * 8];
            #pragma unroll
            for (int j = 0; j < 4; ++j)
                b[j] = *(const bf16x8*)&Bs[ks][(wc + j * 16 + l16) * 32 + quad * 8];
            #pragma unroll
            for (int i = 0; i < 4; ++i)
                #pragma unroll
                for (int j = 0; j < 4; ++j)
                    acc[i][j] = __builtin_amdgcn_mfma_f32_16x16x32_bf16(a[i], b[j], acc[i][j], 0, 0, 0);
        }
        __syncthreads();
    }

    #pragma unroll
    for (int i = 0; i < 4; ++i) {
        #pragma unroll
        for (int j = 0; j < 4; ++j) {
            #pragma unroll
            for (int r = 0; r < 4; ++r) {
                const int row = rowBase + wr + i * 16 + quad * 4 + r;
                const int col = colBase + wc + j * 16 + l16;
                const float v = acc[i][j][r];
                if (OUT_F32_BIAS) ((float*)Cptr)[(size_t)row * N + col] = v + bias[col];
                else              ((bf16*)Cptr)[(size_t)row * N + col] = (bf16)v;
            }
        }
    }
}

// ---------------------------------------------------------------------------
// Attention (round-7 kernel, reverted): S^T-form, q-tile 128, 4 waves x 32
// q-rows, 2 blocks/CU (8 waves/CU for latency hiding), register prefetch of
// next K/V tile. Round-8's fat-wave variant halved LDS traffic but dropped
// to 1 wave/SIMD (grid=256=1 block/CU) and regressed 96->116 us — occupancy
// is the binding constraint, not traffic.
// ---------------------------------------------------------------------------
__global__ __launch_bounds__(256, 2)
void attn_kernel(const bf16* __restrict__ q, bf16* __restrict__ y)
{
    __shared__ bf16 Ks[64 * KSTRIDE];     // 17408 B  [kv][hd]
    __shared__ bf16 Vt[HDIM * VSTRIDE];   // 18432 B  [hd][kv]
    __shared__ bf16 Ps[128 * PSTRIDE];    // 18432 B  [q][kv]

    const int tid  = threadIdx.x;
    const int wave = tid >> 6;     // 0..3
    const int lane = tid & 63;
    const int quad = lane >> 4;
    const int l16  = lane & 15;

    const int qt = blockIdx.x;
    const int h  = blockIdx.y;
    const int bb = blockIdx.z;

    const bf16* qb = q + (size_t)bb * SEQ * DIM + (size_t)h * HDIM;

    // Q fragments -> registers (wave owns q rows [wave*32, wave*32+32)).
    const float qs = 0.12752820031096662f;   // (1/sqrt(128)) * log2(e)
    bf16x8 aq[2][4];
    #pragma unroll
    for (int nt = 0; nt < 2; ++nt) {
        #pragma unroll
        for (int ks = 0; ks < 4; ++ks) {
            const bf16* src = qb + (size_t)(qt * 128 + wave * 32 + nt * 16 + l16) * DIM + ks * 32 + quad * 8;
            bf16x8 v = *(const bf16x8*)src;
            bf16x8 o;
            #pragma unroll
            for (int e = 0; e < 8; ++e) o[e] = (bf16)((float)v[e] * qs);
            aq[nt][ks] = o;
        }
    }

    float lpart[2] = {0.f, 0.f};
    f32x4 yacc[2][8] = {};

    // staging index maps (both conflict-free, round-6 audit)
    const int kr   = tid >> 2;         // kv row 0..63 (Ks path)
    const int koff = (tid & 3) * 32;
    const int sp   = tid & 31;         // kv pair (Vt path)
    const int ss   = tid >> 5;         // hd slice of 16

    const bf16* srcK = qb + (size_t)kr * DIM + koff;
    const bf16* srcV = qb + (size_t)(2 * sp) * DIM + ss * 16;

    // prologue: prefetch tile 0 into registers
    bf16x8 kreg[4], va[2], vb[2];
    #pragma unroll
    for (int c = 0; c < 4; ++c) kreg[c] = *(const bf16x8*)(srcK + c * 8);
    va[0] = *(const bf16x8*)(srcV + 0);
    va[1] = *(const bf16x8*)(srcV + 8);
    vb[0] = *(const bf16x8*)(srcV + DIM + 0);
    vb[1] = *(const bf16x8*)(srcV + DIM + 8);

    for (int kt = 0; kt < SEQ / 64; ++kt) {
        __syncthreads();   // prev iteration done reading Ks/Vt

        // commit prefetched tile to LDS
        #pragma unroll
        for (int c = 0; c < 4; ++c)
            *(bf16x8*)&Ks[kr * KSTRIDE + koff + c * 8] = kreg[c];
        #pragma unroll
        for (int c = 0; c < 2; ++c)
            #pragma unroll
            for (int e = 0; e < 8; ++e)
                *(bf16x2*)&Vt[(ss * 16 + c * 8 + e) * VSTRIDE + 2 * sp] = (bf16x2){va[c][e], vb[c][e]};

        // prefetch NEXT tile (overlaps the compute phase below)
        if (kt + 1 < SEQ / 64) {
            const bf16* nK = srcK + (size_t)(kt + 1) * 64 * DIM;
            const bf16* nV = srcV + (size_t)(kt + 1) * 64 * DIM;
            #pragma unroll
            for (int c = 0; c < 4; ++c) kreg[c] = *(const bf16x8*)(nK + c * 8);
            va[0] = *(const bf16x8*)(nV + 0);
            va[1] = *(const bf16x8*)(nV + 8);
            vb[0] = *(const bf16x8*)(nV + DIM + 0);
            vb[1] = *(const bf16x8*)(nV + DIM + 8);
        }
        __syncthreads();

        // S^T phase per 16-kv strip (mt): MFMA(A=Ks-frag, B=aq).
        // C-layout of S^T: kv = mt*16 + quad*4 + r, q = wave*32 + nt*16 + l16.
        #pragma unroll
        for (int mt = 0; mt < 4; ++mt) {
            bf16x8 ak[4];
            #pragma unroll
            for (int ks = 0; ks < 4; ++ks)
                ak[ks] = *(const bf16x8*)&Ks[(mt * 16 + l16) * KSTRIDE + ks * 32 + quad * 8];
            f32x4 s[2] = {};
            #pragma unroll
            for (int ks = 0; ks < 4; ++ks)
                #pragma unroll
                for (int nt = 0; nt < 2; ++nt)
                    s[nt] = __builtin_amdgcn_mfma_f32_16x16x32_bf16(ak[ks], aq[nt][ks], s[nt], 0, 0, 0);
            #pragma unroll
            for (int nt = 0; nt < 2; ++nt) {
                float p0 = exp2_hw(s[nt][0]);
                float p1 = exp2_hw(s[nt][1]);
                float p2 = exp2_hw(s[nt][2]);
                float p3 = exp2_hw(s[nt][3]);
                lpart[nt] += (p0 + p1) + (p2 + p3);
                *(bf16x4*)&Ps[(wave * 32 + nt * 16 + l16) * PSTRIDE + mt * 16 + quad * 4] =
                    (bf16x4){(bf16)p0, (bf16)p1, (bf16)p2, (bf16)p3};
            }
        }

        // PV: Y += P @ V. A = own-wave P rows (in-wave LDS dep only), B = V^T.
        #pragma unroll
        for (int ks2 = 0; ks2 < 2; ++ks2) {
            bf16x8 ap[2];
            #pragma unroll
            for (int i = 0; i < 2; ++i)
                ap[i] = *(const bf16x8*)&Ps[(wave * 32 + i * 16 + l16) * PSTRIDE + ks2 * 32 + quad * 8];
            #pragma unroll
            for (int n = 0; n < 8; ++n) {
                bf16x8 bv = *(const bf16x8*)&Vt[(n * 16 + l16) * VSTRIDE + ks2 * 32 + quad * 8];
                #pragma unroll
                for (int i = 0; i < 2; ++i)
                    yacc[i][n] = __builtin_amdgcn_mfma_f32_16x16x32_bf16(ap[i], bv, yacc[i][n], 0, 0, 0);
            }
        }
    }

    // denominators: lane holds partial over its 16 kv per q = nt*16 + l16;
    // reduce across the 4 quad-lanes sharing each q.
    float lfull[2];
    #pragma unroll
    for (int nt = 0; nt < 2; ++nt) {
        float l = lpart[nt];
        l += __shfl_xor(l, 16);
        l += __shfl_xor(l, 32);
        lfull[nt] = l;
    }

    // epilogue: yacc C-layout row = wave*32 + i*16 + quad*4 + r (q),
    // col = n*16 + l16 (hd).
    bf16* yb = y + (size_t)bb * SEQ * DIM + (size_t)(qt * 128) * DIM + (size_t)h * HDIM;
    #pragma unroll
    for (int i = 0; i < 2; ++i) {
        #pragma unroll
        for (int r = 0; r < 4; ++r) {
            const float lv  = __shfl(lfull[i], (lane & 48) | (quad * 4 + r));
            const float inv = 1.f / lv;
            const int row = wave * 32 + i * 16 + quad * 4 + r;
            #pragma unroll
            for (int n = 0; n < 8; ++n)
                yb[(size_t)row * DIM + n * 16 + l16] = (bf16)(yacc[i][n][r] * inv);
        }
    }
}

// ---------------------------------------------------------------------------
extern "C" void kernel_launch(void* const* d_in, const int* in_sizes, int n_in,
                              void* d_out, int out_size, void* d_ws, size_t ws_size,
                              hipStream_t stream)
{
    const float* x  = (const float*)d_in[0];
    const float* Wq = (const float*)d_in[1];
    const float* Wo = (const float*)d_in[2];
    const float* bo = (const float*)d_in[3];
    float* out = (float*)d_out;

    const size_t NELEM = (size_t)BATCH * SEQ * DIM;
    bf16* qws = (bf16*)d_ws;
    bf16* xb  = qws + NELEM;        // reused as yws after gemm1
    bf16* yws = xb;
    bf16* Wt  = xb + NELEM;

    const int M = BATCH * SEQ;
    dim3 gg(DIM / 128, M / 128);
    dim3 gt(DIM / 64, DIM / 64);

    cvt_bf16<<<(int)(NELEM / 4 + 255) / 256, 256, 0, stream>>>(x, xb, (int)(NELEM / 4));
    transpose_w<<<gt, 256, 0, stream>>>(Wq, Wt);
    gemm_bt<false><<<gg, 256, 0, stream>>>(xb, Wt, nullptr, qws, M, DIM, DIM);
    transpose_w<<<gt, 256, 0, stream>>>(Wo, Wt);
    attn_kernel<<<dim3(SEQ / 128, NHEAD, BATCH), 256, 0, stream>>>(qws, yws);
    gemm_bt<true><<<gg, 256, 0, stream>>>(yws, Wt, bo, out, M, DIM, DIM);
}

// Round 10
// 279.822 us; speedup vs baseline: 1.0873x; 1.0189x over previous
//
#include <hip/hip_runtime.h>
#include <hip/hip_bf16.h>

#define BATCH 2
#define SEQ   2048
#define DIM   2048
#define NHEAD 16
#define HDIM  128

// LDS strides (elements). Multiples of 8 (16B alignment for b128); bank
// audits in comments at each access site.
#define KSTRIDE 136
#define VSTRIDE 72
#define PSTRIDE 72

typedef __bf16 bf16;
typedef __attribute__((ext_vector_type(2))) __bf16 bf16x2;
typedef __attribute__((ext_vector_type(4))) __bf16 bf16x4;
typedef __attribute__((ext_vector_type(8))) __bf16 bf16x8;
typedef __attribute__((ext_vector_type(4))) float f32x4;

__device__ __forceinline__ void load_lds16(const bf16* g, bf16* l) {
    __builtin_amdgcn_global_load_lds((const __attribute__((address_space(1))) void*)g,
                                     (__attribute__((address_space(3))) void*)l, 16, 0, 0);
}

// v_exp_f32: D = 2^S0 (hardware transcendental)
__device__ __forceinline__ float exp2_hw(float x) { return __builtin_amdgcn_exp2f(x); }

// ---------------------------------------------------------------------------
// Fused prep (single dispatch, tasks run concurrently):
//   blocks [0, 4096):        cvt x fp32 -> xb bf16 (8 elems/thread)
//   blocks [4096, 5120):     transpose Wq -> Wtq (64x64 tiles)
//   blocks [5120, 6144):     transpose Wo -> Wto
// Transpose: write-side paired-k b32 into padded LDS (conflict-free: stride
// 72 elem = 36 words, 36*8 = 0 mod 32 -> k-pair index spans all 32 banks),
// read rows as b128, store coalesced bf16x8.
// ---------------------------------------------------------------------------
__global__ __launch_bounds__(256)
void prep_kernel(const float* __restrict__ x, bf16* __restrict__ xb,
                 const float* __restrict__ Wq, bf16* __restrict__ Wtq,
                 const float* __restrict__ Wo, bf16* __restrict__ Wto)
{
    __shared__ bf16 T[64 * 72];
    const int bid = blockIdx.x;
    if (bid < 4096) {
        const size_t i = ((size_t)bid * 256 + threadIdx.x) * 8;
        const float4 f0 = *(const float4*)(x + i);
        const float4 f1 = *(const float4*)(x + i + 4);
        *(bf16x8*)(xb + i) = (bf16x8){(bf16)f0.x, (bf16)f0.y, (bf16)f0.z, (bf16)f0.w,
                                      (bf16)f1.x, (bf16)f1.y, (bf16)f1.z, (bf16)f1.w};
        return;
    }
    int t = bid - 4096;
    const float* W  = (t < 1024) ? Wq : Wo;
    bf16*        Wt = (t < 1024) ? Wtq : Wto;
    t &= 1023;
    const int kb = (t >> 5) * 64, nb = (t & 31) * 64;

    const int a = threadIdx.x & 31;     // k-pair index
    const int g = threadIdx.x >> 5;     // n-slice 0..7
    {
        const float* s0 = W + (size_t)(kb + 2 * a) * DIM + nb + g * 8;
        const float4 r0a = *(const float4*)(s0);
        const float4 r0b = *(const float4*)(s0 + 4);
        const float4 r1a = *(const float4*)(s0 + DIM);
        const float4 r1b = *(const float4*)(s0 + DIM + 4);
        float v0[8] = {r0a.x, r0a.y, r0a.z, r0a.w, r0b.x, r0b.y, r0b.z, r0b.w};
        float v1[8] = {r1a.x, r1a.y, r1a.z, r1a.w, r1b.x, r1b.y, r1b.z, r1b.w};
        #pragma unroll
        for (int i = 0; i < 8; ++i)
            *(bf16x2*)&T[(g * 8 + i) * 72 + 2 * a] = (bf16x2){(bf16)v0[i], (bf16)v1[i]};
    }
    __syncthreads();

    const int r  = threadIdx.x >> 2;          // output n row 0..63
    const int k0 = (threadIdx.x & 3) * 16;    // k chunk
    bf16x8 o0 = *(const bf16x8*)&T[r * 72 + k0];
    bf16x8 o1 = *(const bf16x8*)&T[r * 72 + k0 + 8];
    *(bf16x8*)(Wt + (size_t)(nb + r) * DIM + kb + k0)     = o0;
    *(bf16x8*)(Wt + (size_t)(nb + r) * DIM + kb + k0 + 8) = o1;
}

// ---------------------------------------------------------------------------
// GEMM: C[M,N] = A[M,K] @ Bt[N,K]^T, bf16 in. BK=64 (two [128][32] half
// buffers keep the m97 bank layout). 128x128 tile, 4 waves 2x2, 4x4 accs,
// global_load_lds width=16.
// ---------------------------------------------------------------------------
template<bool OUT_F32_BIAS>
__global__ __launch_bounds__(256)
void gemm_bt(const bf16* __restrict__ A, const bf16* __restrict__ Bt,
             const float* __restrict__ bias, void* __restrict__ Cptr,
             int M, int N, int K)
{
    __shared__ bf16 As[2][128 * 32];   // [k-half][row][32]
    __shared__ bf16 Bs[2][128 * 32];

    const int tid  = threadIdx.x;
    const int wave = tid >> 6;
    const int lane = tid & 63;
    const int quad = lane >> 4;
    const int l16  = lane & 15;
    const int wr   = (wave >> 1) * 64;
    const int wc   = (wave & 1) * 64;
    const int rowBase = blockIdx.y * 128;
    const int colBase = blockIdx.x * 128;

    const int srow = lane >> 2;
    const int scol = (lane & 3) * 8;
    const bf16* aBase = A  + (size_t)(rowBase + wave * 16 + srow) * K + scol;
    const bf16* bBase = Bt + (size_t)(colBase + wave * 16 + srow) * K + scol;

    f32x4 acc[4][4] = {};

    for (int k0 = 0; k0 < K; k0 += 64) {
        #pragma unroll
        for (int rh = 0; rh < 2; ++rh) {
            #pragma unroll
            for (int kh = 0; kh < 2; ++kh) {
                load_lds16(aBase + (size_t)rh * 64 * K + k0 + kh * 32,
                           (bf16*)As[kh] + (rh * 64 + wave * 16) * 32);
                load_lds16(bBase + (size_t)rh * 64 * K + k0 + kh * 32,
                           (bf16*)Bs[kh] + (rh * 64 + wave * 16) * 32);
            }
        }
        __syncthreads();

        #pragma unroll
        for (int ks = 0; ks < 2; ++ks) {
            bf16x8 a[4], b[4];
            #pragma unroll
            for (int i = 0; i < 4; ++i)
                a[i] = *(const bf16x8*)&As[ks][(wr + i * 16 + l16) * 32 + quad * 8];
            #pragma unroll
            for (int j = 0; j < 4; ++j)
                b[j] = *(const bf16x8*)&Bs[ks][(wc + j * 16 + l16) * 32 + quad * 8];
            #pragma unroll
            for (int i = 0; i < 4; ++i)
                #pragma unroll
                for (int j = 0; j < 4; ++j)
                    acc[i][j] = __builtin_amdgcn_mfma_f32_16x16x32_bf16(a[i], b[j], acc[i][j], 0, 0, 0);
        }
        __syncthreads();
    }

    #pragma unroll
    for (int i = 0; i < 4; ++i) {
        #pragma unroll
        for (int j = 0; j < 4; ++j) {
            #pragma unroll
            for (int r = 0; r < 4; ++r) {
                const int row = rowBase + wr + i * 16 + quad * 4 + r;
                const int col = colBase + wc + j * 16 + l16;
                const float v = acc[i][j][r];
                if (OUT_F32_BIAS) ((float*)Cptr)[(size_t)row * N + col] = v + bias[col];
                else              ((bf16*)Cptr)[(size_t)row * N + col] = (bf16)v;
            }
        }
    }
}

// ---------------------------------------------------------------------------
// Attention (round-7 structure, unchanged inner loops): S^T-form, q-tile 128,
// 4 waves x 32 q-rows, 2 blocks/CU, register prefetch of next K/V tile.
// NEW: XCD-aware block swizzle — flat 1D grid of 512; physical block p lands
// on XCD p&7 (round-robin assumption; a wrong assumption only costs locality,
// never correctness). All 16 q-tiles of one (b,h) map to one XCD so the
// head's 1 MB K/V stream stays resident in that XCD's 4 MB L2.
// ---------------------------------------------------------------------------
__global__ __launch_bounds__(256, 2)
void attn_kernel(const bf16* __restrict__ q, bf16* __restrict__ y)
{
    __shared__ bf16 Ks[64 * KSTRIDE];     // 17408 B  [kv][hd]
    __shared__ bf16 Vt[HDIM * VSTRIDE];   // 18432 B  [hd][kv]
    __shared__ bf16 Ps[128 * PSTRIDE];    // 18432 B  [q][kv]

    const int tid  = threadIdx.x;
    const int wave = tid >> 6;     // 0..3
    const int lane = tid & 63;
    const int quad = lane >> 4;
    const int l16  = lane & 15;

    // XCD swizzle: p -> (qt, h, b) with all qt of a (b,h) on one XCD.
    const int p   = blockIdx.x;
    const int xcd = p & 7;
    const int pos = p >> 3;
    const int g   = xcd * 4 + (pos & 3);   // (b,h) group 0..31
    const int qt  = pos >> 2;              // 0..15
    const int h   = g & 15;
    const int bb  = g >> 4;

    const bf16* qb = q + (size_t)bb * SEQ * DIM + (size_t)h * HDIM;

    // Q fragments -> registers (wave owns q rows [wave*32, wave*32+32)).
    const float qs = 0.12752820031096662f;   // (1/sqrt(128)) * log2(e)
    bf16x8 aq[2][4];
    #pragma unroll
    for (int nt = 0; nt < 2; ++nt) {
        #pragma unroll
        for (int ks = 0; ks < 4; ++ks) {
            const bf16* src = qb + (size_t)(qt * 128 + wave * 32 + nt * 16 + l16) * DIM + ks * 32 + quad * 8;
            bf16x8 v = *(const bf16x8*)src;
            bf16x8 o;
            #pragma unroll
            for (int e = 0; e < 8; ++e) o[e] = (bf16)((float)v[e] * qs);
            aq[nt][ks] = o;
        }
    }

    float lpart[2] = {0.f, 0.f};
    f32x4 yacc[2][8] = {};

    // staging index maps (both conflict-free, round-6 audit)
    const int kr   = tid >> 2;         // kv row 0..63 (Ks path)
    const int koff = (tid & 3) * 32;
    const int sp   = tid & 31;         // kv pair (Vt path)
    const int ss   = tid >> 5;         // hd slice of 16

    const bf16* srcK = qb + (size_t)kr * DIM + koff;
    const bf16* srcV = qb + (size_t)(2 * sp) * DIM + ss * 16;

    // prologue: prefetch tile 0 into registers
    bf16x8 kreg[4], va[2], vb[2];
    #pragma unroll
    for (int c = 0; c < 4; ++c) kreg[c] = *(const bf16x8*)(srcK + c * 8);
    va[0] = *(const bf16x8*)(srcV + 0);
    va[1] = *(const bf16x8*)(srcV + 8);
    vb[0] = *(const bf16x8*)(srcV + DIM + 0);
    vb[1] = *(const bf16x8*)(srcV + DIM + 8);

    for (int kt = 0; kt < SEQ / 64; ++kt) {
        __syncthreads();   // prev iteration done reading Ks/Vt

        // commit prefetched tile to LDS
        #pragma unroll
        for (int c = 0; c < 4; ++c)
            *(bf16x8*)&Ks[kr * KSTRIDE + koff + c * 8] = kreg[c];
        #pragma unroll
        for (int c = 0; c < 2; ++c)
            #pragma unroll
            for (int e = 0; e < 8; ++e)
                *(bf16x2*)&Vt[(ss * 16 + c * 8 + e) * VSTRIDE + 2 * sp] = (bf16x2){va[c][e], vb[c][e]};

        // prefetch NEXT tile (overlaps the compute phase below)
        if (kt + 1 < SEQ / 64) {
            const bf16* nK = srcK + (size_t)(kt + 1) * 64 * DIM;
            const bf16* nV = srcV + (size_t)(kt + 1) * 64 * DIM;
            #pragma unroll
            for (int c = 0; c < 4; ++c) kreg[c] = *(const bf16x8*)(nK + c * 8);
            va[0] = *(const bf16x8*)(nV + 0);
            va[1] = *(const bf16x8*)(nV + 8);
            vb[0] = *(const bf16x8*)(nV + DIM + 0);
            vb[1] = *(const bf16x8*)(nV + DIM + 8);
        }
        __syncthreads();

        // S^T phase per 16-kv strip (mt): MFMA(A=Ks-frag, B=aq).
        // C-layout of S^T: kv = mt*16 + quad*4 + r, q = wave*32 + nt*16 + l16.
        #pragma unroll
        for (int mt = 0; mt < 4; ++mt) {
            bf16x8 ak[4];
            #pragma unroll
            for (int ks = 0; ks < 4; ++ks)
                ak[ks] = *(const bf16x8*)&Ks[(mt * 16 + l16) * KSTRIDE + ks * 32 + quad * 8];
            f32x4 s[2] = {};
            #pragma unroll
            for (int ks = 0; ks < 4; ++ks)
                #pragma unroll
                for (int nt = 0; nt < 2; ++nt)
                    s[nt] = __builtin_amdgcn_mfma_f32_16x16x32_bf16(ak[ks], aq[nt][ks], s[nt], 0, 0, 0);
            #pragma unroll
            for (int nt = 0; nt < 2; ++nt) {
                float p0 = exp2_hw(s[nt][0]);
                float p1 = exp2_hw(s[nt][1]);
                float p2 = exp2_hw(s[nt][2]);
                float p3 = exp2_hw(s[nt][3]);
                lpart[nt] += (p0 + p1) + (p2 + p3);
                *(bf16x4*)&Ps[(wave * 32 + nt * 16 + l16) * PSTRIDE + mt * 16 + quad * 4] =
                    (bf16x4){(bf16)p0, (bf16)p1, (bf16)p2, (bf16)p3};
            }
        }

        // PV: Y += P @ V. A = own-wave P rows (in-wave LDS dep only), B = V^T.
        #pragma unroll
        for (int ks2 = 0; ks2 < 2; ++ks2) {
            bf16x8 ap[2];
            #pragma unroll
            for (int i = 0; i < 2; ++i)
                ap[i] = *(const bf16x8*)&Ps[(wave * 32 + i * 16 + l16) * PSTRIDE + ks2 * 32 + quad * 8];
            #pragma unroll
            for (int n = 0; n < 8; ++n) {
                bf16x8 bv = *(const bf16x8*)&Vt[(n * 16 + l16) * VSTRIDE + ks2 * 32 + quad * 8];
                #pragma unroll
                for (int i = 0; i < 2; ++i)
                    yacc[i][n] = __builtin_amdgcn_mfma_f32_16x16x32_bf16(ap[i], bv, yacc[i][n], 0, 0, 0);
            }
        }
    }

    // denominators: lane holds partial over its 16 kv per q = nt*16 + l16;
    // reduce across the 4 quad-lanes sharing each q.
    float lfull[2];
    #pragma unroll
    for (int nt = 0; nt < 2; ++nt) {
        float l = lpart[nt];
        l += __shfl_xor(l, 16);
        l += __shfl_xor(l, 32);
        lfull[nt] = l;
    }

    // epilogue: yacc C-layout row = wave*32 + i*16 + quad*4 + r (q),
    // col = n*16 + l16 (hd).
    bf16* yb = y + (size_t)bb * SEQ * DIM + (size_t)(qt * 128) * DIM + (size_t)h * HDIM;
    #pragma unroll
    for (int i = 0; i < 2; ++i) {
        #pragma unroll
        for (int r = 0; r < 4; ++r) {
            const float lv  = __shfl(lfull[i], (lane & 48) | (quad * 4 + r));
            const float inv = 1.f / lv;
            const int row = wave * 32 + i * 16 + quad * 4 + r;
            #pragma unroll
            for (int n = 0; n < 8; ++n)
                yb[(size_t)row * DIM + n * 16 + l16] = (bf16)(yacc[i][n][r] * inv);
        }
    }
}

// ---------------------------------------------------------------------------
// Workspace / scratch layout (41.94 MB ws, same footprint as prior rounds):
//   ws[0 .. N)        qws  (gemm1 out, attn in)           N = 16.78 MB
//   ws[N .. 2N)       yws  (attn out, gemm2 in); its first 8.39 MB doubles
//                     as Wtq (prep writes, gemm1 reads, attn clobbers AFTER)
//   ws[2N .. 2N+W)    Wto  (prep writes, gemm2 reads)     W = 8.39 MB
//   d_out[0 .. N)     xb   (bf16 scratch; dead before gemm2 overwrites d_out)
// ---------------------------------------------------------------------------
extern "C" void kernel_launch(void* const* d_in, const int* in_sizes, int n_in,
                              void* d_out, int out_size, void* d_ws, size_t ws_size,
                              hipStream_t stream)
{
    const float* x  = (const float*)d_in[0];
    const float* Wq = (const float*)d_in[1];
    const float* Wo = (const float*)d_in[2];
    const float* bo = (const float*)d_in[3];
    float* out = (float*)d_out;

    const size_t NELEM = (size_t)BATCH * SEQ * DIM;
    bf16* qws = (bf16*)d_ws;
    bf16* yws = qws + NELEM;
    bf16* Wtq = yws;                 // aliased: safe, gemm1 precedes attn
    bf16* Wto = qws + 2 * NELEM;
    bf16* xb  = (bf16*)d_out;        // scratch inside d_out, dead by gemm2

    const int M = BATCH * SEQ;
    dim3 gg(DIM / 128, M / 128);

    prep_kernel<<<6144, 256, 0, stream>>>(x, xb, Wq, Wtq, Wo, Wto);
    gemm_bt<false><<<gg, 256, 0, stream>>>(xb, Wtq, nullptr, qws, M, DIM, DIM);
    attn_kernel<<<512, 256, 0, stream>>>(qws, yws);
    gemm_bt<true><<<gg, 256, 0, stream>>>(yws, Wto, bo, out, M, DIM, DIM);
}